// Round 11
// baseline (271.007 us; speedup 1.0000x reference)
//
#include <hip/hip_runtime.h>
#include <hip/hip_bf16.h>
#include <cmath>

// Problem constants
#define B_   8
#define N_   4096
#define DIN1 64
#define DHID 128
#define DOUT2 64
#define MAXDEG 256

// Group-TOP lanes (15,31,47,63): DPP row_shr accumulates the row sum at the
// highest lane of each 16-lane row (lane i receives lane i-N; sums flow UP).
#define GLTOPMASK 0x8000800080008000ULL

// DPP row_shr add: p[i] += p[i-SH] within each 16-lane row (0 shifted in).
// Pure VALU (no LDS pipe). After shr 8,4,2,1 the row sum is in lane 15.
template <int SH>
__device__ __forceinline__ float dpp_shr_add(float p) {
    int t = __builtin_amdgcn_update_dpp(0, __float_as_int(p),
                                        0x110 | SH, 0xF, 0xF, true);
    return p + __int_as_float(t);
}
__device__ __forceinline__ float dpp_reduce16(float p) {
    p = dpp_shr_add<8>(p);
    p = dpp_shr_add<4>(p);
    p = dpp_shr_add<2>(p);
    p = dpp_shr_add<1>(p);
    return p;   // valid on lane 15 of each 16-lane row (TOP lane)
}

// ---------------------------------------------------------------------------
// Kernel 1: adjacency -> fixed-stride neighbor lists (float4 scan).
// ---------------------------------------------------------------------------
__global__ __launch_bounds__(256) void k_build_csr(
    const float* __restrict__ graph, int* __restrict__ cnt, int* __restrict__ idx)
{
    const int n = blockIdx.x;
    __shared__ int lcnt;
    if (threadIdx.x == 0) lcnt = 0;
    __syncthreads();
    const float4* row4 = (const float4*)(graph + (size_t)n * N_);
    int* myidx = idx + (size_t)n * MAXDEG;
    for (int m4 = threadIdx.x; m4 < N_ / 4; m4 += 256) {
        float4 g = row4[m4];
        if (g.x != 0.0f) { int p = atomicAdd(&lcnt, 1); if (p < MAXDEG) myidx[p] = 4 * m4; }
        if (g.y != 0.0f) { int p = atomicAdd(&lcnt, 1); if (p < MAXDEG) myidx[p] = 4 * m4 + 1; }
        if (g.z != 0.0f) { int p = atomicAdd(&lcnt, 1); if (p < MAXDEG) myidx[p] = 4 * m4 + 2; }
        if (g.w != 0.0f) { int p = atomicAdd(&lcnt, 1); if (p < MAXDEG) myidx[p] = 4 * m4 + 3; }
    }
    __syncthreads();
    if (threadIdx.x == 0) cnt[n] = (lcnt < MAXDEG) ? lcnt : MAXDEG;
}

// ---------------------------------------------------------------------------
// Kernel 2: register-tiled linear. out[r,k] = sum_d x[r,d]*W[k,d].
// W staged (transposed) once per block, swept over 64 rows in 2 chunks.
// ---------------------------------------------------------------------------
template <int DIN, int DOUT>
__global__ __launch_bounds__(256) void k_linear(
    const float* __restrict__ x, const float* __restrict__ W,
    float* __restrict__ out)
{
    constexpr int CG = DOUT / 4;
    constexpr int RG = 256 / CG;
    constexpr int TR = 32 / RG;

    __shared__ float sWt[DIN][DOUT + 4];

    const int t = threadIdx.x;
    const float4* W4 = (const float4*)W;
    for (int i = t; i < DOUT * (DIN / 4); i += 256) {
        int kk = i / (DIN / 4);
        int d4 = i % (DIN / 4);
        float4 w = W4[i];
        sWt[4 * d4 + 0][kk] = w.x;
        sWt[4 * d4 + 1][kk] = w.y;
        sWt[4 * d4 + 2][kk] = w.z;
        sWt[4 * d4 + 3][kk] = w.w;
    }
    __syncthreads();

    const int rg = t / CG;
    const int c  = t % CG;
    const float4* x4 = (const float4*)x;

    for (int chunk = 0; chunk < 2; ++chunk) {
        const int base = blockIdx.x * 64 + chunk * 32;
        float acc[TR][4];
#pragma unroll
        for (int i = 0; i < TR; ++i)
#pragma unroll
            for (int j = 0; j < 4; ++j) acc[i][j] = 0.0f;

        for (int d4 = 0; d4 < DIN / 4; ++d4) {
            float4 xf[TR];
#pragma unroll
            for (int i = 0; i < TR; ++i)
                xf[i] = x4[(size_t)(base + rg * TR + i) * (DIN / 4) + d4];
            float4 wf[4];
#pragma unroll
            for (int dd = 0; dd < 4; ++dd)
                wf[dd] = *(const float4*)&sWt[4 * d4 + dd][4 * c];
#pragma unroll
            for (int i = 0; i < TR; ++i) {
                acc[i][0] += xf[i].x * wf[0].x + xf[i].y * wf[1].x + xf[i].z * wf[2].x + xf[i].w * wf[3].x;
                acc[i][1] += xf[i].x * wf[0].y + xf[i].y * wf[1].y + xf[i].z * wf[2].y + xf[i].w * wf[3].y;
                acc[i][2] += xf[i].x * wf[0].z + xf[i].y * wf[1].z + xf[i].z * wf[2].z + xf[i].w * wf[3].z;
                acc[i][3] += xf[i].x * wf[0].w + xf[i].y * wf[1].w + xf[i].z * wf[2].w + xf[i].w * wf[3].w;
            }
        }
#pragma unroll
        for (int i = 0; i < TR; ++i) {
            float4 o = {acc[i][0], acc[i][1], acc[i][2], acc[i][3]};
            ((float4*)out)[(size_t)(base + rg * TR + i) * CG + c] = o;
        }
    }
}

// ---------------------------------------------------------------------------
// Kernel 3: online-softmax sparse masked attention, DPP edition (fixed).
// One query per wave; 4 groups of 16 lanes stream disjoint neighbor subsets
// (each row read from L2 once). Dot reduced with 4 DPP row_shr adds (pure
// VALU; row sum lands in the TOP lane of each row); skip test = ballot on
// lanes 15/31/47/63. m initialized to self-score ||q||^2, group-uniform.
// Hot loop: load + dot + 4 dpp-adds + 1 ballot-test. Terms with p <= m-100
// underflow exp to exactly 0.0f -> skipping is bit-neutral; taken path is
// the full two-sided flash update (exact for any data; false-positive
// triggers just run it redundantly). 32-bit pre-scaled byte offsets in LDS;
// 12 zero-offset pads -> guard-free depth-2 prefetch. Exact torch
// masked_fill(s==0) semantics; all-masked fallback = rare in-kernel path.
// ---------------------------------------------------------------------------
template <int D, bool RELU>
__global__ __launch_bounds__(256) void k_attn(
    const float* __restrict__ h, const int* __restrict__ cnt,
    const int* __restrict__ idx, const float* __restrict__ bias,
    float* __restrict__ out)
{
    constexpr int V  = D / 4;    // float4s per row (32 or 16)
    constexpr int NF = V / 16;   // float4s per lane (2 or 1)
    constexpr int RB = D * 4;    // row bytes (512 or 256)

    const int bid  = blockIdx.x;
    const int b    = bid & 7;                    // batch -> XCD pinning
    const int wave = threadIdx.x >> 6;
    const int lane = threadIdx.x & 63;
    const int n    = (bid >> 3) * 4 + wave;      // one query per wave
    const int grp  = lane >> 4;                  // 4 neighbor streams
    const int gl   = lane & 15;
    const int gtop = (lane & 48) + 15;           // group's TOP lane (row sum)

    __shared__ int s_off[4][MAXDEG + 12];        // wave-private byte offsets

    const int k = cnt[n];
    const int* __restrict__ myidx = idx + (size_t)n * MAXDEG;
    for (int j = lane; j < k; j += 64) s_off[wave][j] = myidx[j] * RB;
    if (lane < 12) s_off[wave][k + lane] = 0;    // pad: safe prefetch targets

    const char* __restrict__ hb = (const char*)h + (size_t)b * N_ * RB;
    const int lb = gl * 16;                       // lane's byte slot in row

    float4 qf[NF];
#pragma unroll
    for (int i = 0; i < NF; ++i)
        qf[i] = *(const float4*)(hb + (size_t)n * RB + lb + 256 * i);

    // self-score init: m = ||q||^2, broadcast from TOP lane (group-uniform)
    float m;
    {
        float p = 0.0f;
#pragma unroll
        for (int i = 0; i < NF; ++i)
            p += qf[i].x * qf[i].x + qf[i].y * qf[i].y
               + qf[i].z * qf[i].z + qf[i].w * qf[i].w;
        p = dpp_reduce16(p);
        const float pb = __shfl(p, gtop, 64);
        m = (pb != 0.0f) ? pb : -INFINITY;
    }
    float mt = m - 100.0f;                       // skip threshold (uniform)
    float s = 0.0f;
    float4 acc[NF];
#pragma unroll
    for (int i = 0; i < NF; ++i) acc[i] = {0.0f, 0.0f, 0.0f, 0.0f};

    auto loadrow = [&](float4 (&r)[NF], int j) {
        const char* hm = hb + s_off[wave][j];
#pragma unroll
        for (int i = 0; i < NF; ++i) r[i] = *(const float4*)(hm + lb + 256 * i);
    };
    auto process = [&](const float4 (&cur)[NF]) {
        float p = 0.0f;
#pragma unroll
        for (int i = 0; i < NF; ++i)
            p += qf[i].x * cur[i].x + qf[i].y * cur[i].y
               + qf[i].z * cur[i].z + qf[i].w * cur[i].w;
        p = dpp_reduce16(p);                      // TOP lane holds true sum
        // skip unless some group's TRUE sum (top lane) is within 100 of max
        if (__builtin_expect((__ballot(p > mt) & GLTOPMASK) != 0ULL, 0)) {
            const float pb = __shfl(p, gtop, 64); // true group sum, uniform
            const bool valid = (pb != 0.0f);      // dot==0 => masked (torch)
            const float pm   = valid ? pb : m;
            const float newm = fmaxf(m, pm);
            const float f = (m == newm) ? 1.0f : __expf(m - newm);
            const float e = valid ? __expf(pb - newm) : 0.0f;
            s = s * f + e;
#pragma unroll
            for (int i = 0; i < NF; ++i) {
                acc[i].x = acc[i].x * f + e * cur[i].x;
                acc[i].y = acc[i].y * f + e * cur[i].y;
                acc[i].z = acc[i].z * f + e * cur[i].z;
                acc[i].w = acc[i].w * f + e * cur[i].w;
            }
            m = newm;
            mt = m - 100.0f;
        }
    };

    // depth-2 guard-free pipeline (pad makes overshoot loads safe)
    {
        float4 r0[NF], r1[NF], r2[NF];
        loadrow(r0, grp);
        loadrow(r1, grp + 4);
        int j = grp;
        while (j < k) {
            loadrow(r2, j + 8);
            process(r0);
            j += 4; if (j >= k) break;
            loadrow(r0, j + 8);
            process(r1);
            j += 4; if (j >= k) break;
            loadrow(r1, j + 8);
            process(r2);
            j += 4;
        }
    }

    // merge the 4 group states (xor 16, 32); all 64 lanes converge
#pragma unroll
    for (int mask = 16; mask <= 32; mask <<= 1) {
        const float m2 = __shfl_xor(m, mask, 64);
        const float s2 = __shfl_xor(s, mask, 64);
        float4 a2[NF];
#pragma unroll
        for (int i = 0; i < NF; ++i) {
            a2[i].x = __shfl_xor(acc[i].x, mask, 64);
            a2[i].y = __shfl_xor(acc[i].y, mask, 64);
            a2[i].z = __shfl_xor(acc[i].z, mask, 64);
            a2[i].w = __shfl_xor(acc[i].w, mask, 64);
        }
        const float mm = fmaxf(m, m2);
        const float f1 = (m  == mm) ? 1.0f : __expf(m  - mm);  // -inf guard
        const float f2 = (m2 == mm) ? 1.0f : __expf(m2 - mm);
        s = s * f1 + s2 * f2;
#pragma unroll
        for (int i = 0; i < NF; ++i) {
            acc[i].x = acc[i].x * f1 + a2[i].x * f2;
            acc[i].y = acc[i].y * f1 + a2[i].y * f2;
            acc[i].z = acc[i].z * f1 + a2[i].z * f2;
            acc[i].w = acc[i].w * f1 + a2[i].w * f2;
        }
        m = mm;
    }

    if (s > 0.0f) {
        // normal epilogue: group 0 (lanes 0..15) writes the row
        if (grp == 0) {
            const float4* bias4 = (const float4*)bias;
            const float inv = 1.0f / s;
#pragma unroll
            for (int i = 0; i < NF; ++i) {
                const float4 bi = bias4[gl + 16 * i];
                float4 o;
                o.x = acc[i].x * inv + bi.x;
                o.y = acc[i].y * inv + bi.y;
                o.z = acc[i].z * inv + bi.z;
                o.w = acc[i].w * inv + bi.w;
                if (RELU) {
                    o.x = fmaxf(o.x, 0.0f); o.y = fmaxf(o.y, 0.0f);
                    o.z = fmaxf(o.z, 0.0f); o.w = fmaxf(o.w, 0.0f);
                }
                ((float4*)out)[((size_t)b * N_ + n) * V + gl + 16 * i] = o;
            }
        }
    } else {
        // RARE path (all scores masked): uniform softmax over all N rows ->
        // column mean of h[b]. Never taken unless the whole q row is zero.
        const float4* hb4 = (const float4*)hb;
        constexpr int RS = 64 / V;
        const int sl = lane % V;
        const int rs = lane / V;
        float4 a = {0.0f, 0.0f, 0.0f, 0.0f};
        for (int row = rs; row < N_; row += RS) {
            float4 v = hb4[(size_t)row * V + sl];
            a.x += v.x; a.y += v.y; a.z += v.z; a.w += v.w;
        }
#pragma unroll
        for (int mask = V; mask < 64; mask <<= 1) {
            a.x += __shfl_xor(a.x, mask, 64);
            a.y += __shfl_xor(a.y, mask, 64);
            a.z += __shfl_xor(a.z, mask, 64);
            a.w += __shfl_xor(a.w, mask, 64);
        }
        if (lane < V) {
            constexpr float invN = 1.0f / (float)N_;
            const float4 bi = ((const float4*)bias)[sl];
            float4 o;
            o.x = a.x * invN + bi.x;
            o.y = a.y * invN + bi.y;
            o.z = a.z * invN + bi.z;
            o.w = a.w * invN + bi.w;
            if (RELU) {
                o.x = fmaxf(o.x, 0.0f); o.y = fmaxf(o.y, 0.0f);
                o.z = fmaxf(o.z, 0.0f); o.w = fmaxf(o.w, 0.0f);
            }
            ((float4*)out)[((size_t)b * N_ + n) * V + sl] = o;
        }
    }
}

// ---------------------------------------------------------------------------
// Launch
// ---------------------------------------------------------------------------
extern "C" void kernel_launch(void* const* d_in, const int* in_sizes, int n_in,
                              void* d_out, int out_size, void* d_ws, size_t ws_size,
                              hipStream_t stream) {
    (void)in_sizes; (void)n_in; (void)out_size; (void)ws_size;

    const float* flow_x = (const float*)d_in[0];
    const float* graph  = (const float*)d_in[1];
    const float* W1     = (const float*)d_in[2];
    const float* b1     = (const float*)d_in[3];
    const float* W2     = (const float*)d_in[4];
    const float* b2     = (const float*)d_in[5];
    float* out = (float*)d_out;

    char* p = (char*)d_ws;
    auto carve = [&](size_t bytes) -> void* {
        void* r = (void*)p;
        p += (bytes + 255) & ~(size_t)255;
        return r;
    };
    int*   nbr_cnt = (int*)carve((size_t)N_ * sizeof(int));
    int*   nbr_idx = (int*)carve((size_t)N_ * MAXDEG * sizeof(int));
    float* h1      = (float*)carve((size_t)B_ * N_ * DHID * sizeof(float));
    float* x2      = (float*)carve((size_t)B_ * N_ * DHID * sizeof(float));
    float* h2      = (float*)carve((size_t)B_ * N_ * DOUT2 * sizeof(float));

    // 1. adjacency -> neighbor lists
    k_build_csr<<<N_, 256, 0, stream>>>(graph, nbr_cnt, nbr_idx);

    // 2. layer 1 linear (64 rows/block)
    k_linear<DIN1, DHID><<<(B_ * N_) / 64, 256, 0, stream>>>(flow_x, W1, h1);

    // 3. layer 1 attention + bias + relu (one query per wave)
    k_attn<DHID, true><<<N_ * B_ / 4, 256, 0, stream>>>(h1, nbr_cnt, nbr_idx, b1, x2);

    // 4. layer 2 linear (64 rows/block)
    k_linear<DHID, DOUT2><<<(B_ * N_) / 64, 256, 0, stream>>>(x2, W2, h2);

    // 5. layer 2 attention + bias -> d_out  ([B,N,1,64] is flat-identical)
    k_attn<DOUT2, false><<<N_ * B_ / 4, 256, 0, stream>>>(h2, nbr_cnt, nbr_idx, b2, out);
}

// Round 12
// 265.719 us; speedup vs baseline: 1.0199x; 1.0199x over previous
//
#include <hip/hip_runtime.h>
#include <hip/hip_bf16.h>
#include <cmath>

// Problem constants
#define B_   8
#define N_   4096
#define DIN1 64
#define DHID 128
#define DOUT2 64
#define MAXDEG 256

// Group-TOP lanes (15,31,47,63): DPP row_shr accumulates the row sum at the
// highest lane of each 16-lane row (lane i receives lane i-N; sums flow UP).
#define GLTOPMASK 0x8000800080008000ULL

template <int SH>
__device__ __forceinline__ float dpp_shr_add(float p) {
    int t = __builtin_amdgcn_update_dpp(0, __float_as_int(p),
                                        0x110 | SH, 0xF, 0xF, true);
    return p + __int_as_float(t);
}
__device__ __forceinline__ float dpp_reduce16(float p) {
    p = dpp_shr_add<8>(p);
    p = dpp_shr_add<4>(p);
    p = dpp_shr_add<2>(p);
    p = dpp_shr_add<1>(p);
    return p;   // valid on lane 15 of each 16-lane row (TOP lane)
}

// ---------------------------------------------------------------------------
// Kernel 1: adjacency -> neighbor lists. One WAVE per row; ballot+mbcnt
// compaction (no LDS, no atomics, no barriers). List order within a row is
// ascending; softmax is order-independent so any order is correct.
// ---------------------------------------------------------------------------
__global__ __launch_bounds__(256) void k_build_csr(
    const float* __restrict__ graph, int* __restrict__ cnt, int* __restrict__ idx)
{
    const int wave = threadIdx.x >> 6;
    const int lane = threadIdx.x & 63;
    const int n = blockIdx.x * 4 + wave;
    const unsigned long long below_mask = (1ULL << lane) - 1ULL;

    const float4* __restrict__ row4 = (const float4*)(graph + (size_t)n * N_);
    int* __restrict__ myidx = idx + (size_t)n * MAXDEG;

    int base = 0;
    for (int it = 0; it < N_ / 256; ++it) {      // 16 iterations
        const int i4 = it * 64 + lane;
        float4 g = row4[i4];
        const int e = 4 * i4;
#pragma unroll
        for (int c = 0; c < 4; ++c) {
            const float gc = (c == 0) ? g.x : (c == 1) ? g.y : (c == 2) ? g.z : g.w;
            const unsigned long long mk = __ballot(gc != 0.0f);
            const int pos = base + __popcll(mk & below_mask);
            if (gc != 0.0f && pos < MAXDEG) myidx[pos] = e + c;
            base += __popcll(mk);                // wave-uniform
        }
    }
    if (lane == 0) cnt[n] = (base < MAXDEG) ? base : MAXDEG;
}

// ---------------------------------------------------------------------------
// Kernel 2: register-tiled linear. out[r,k] = sum_d x[r,d]*W[k,d].
// 32 rows/block (1024 blocks -> better latency hiding than 64-row variant).
// ---------------------------------------------------------------------------
template <int DIN, int DOUT>
__global__ __launch_bounds__(256) void k_linear(
    const float* __restrict__ x, const float* __restrict__ W,
    float* __restrict__ out)
{
    constexpr int CG = DOUT / 4;
    constexpr int RG = 256 / CG;
    constexpr int TR = 32 / RG;

    __shared__ float sWt[DIN][DOUT + 4];

    const int t = threadIdx.x;
    const float4* W4 = (const float4*)W;
    for (int i = t; i < DOUT * (DIN / 4); i += 256) {
        int kk = i / (DIN / 4);
        int d4 = i % (DIN / 4);
        float4 w = W4[i];
        sWt[4 * d4 + 0][kk] = w.x;
        sWt[4 * d4 + 1][kk] = w.y;
        sWt[4 * d4 + 2][kk] = w.z;
        sWt[4 * d4 + 3][kk] = w.w;
    }
    __syncthreads();

    const int rg = t / CG;
    const int c  = t % CG;
    const int base = blockIdx.x * 32;
    const float4* x4 = (const float4*)x;

    float acc[TR][4];
#pragma unroll
    for (int i = 0; i < TR; ++i)
#pragma unroll
        for (int j = 0; j < 4; ++j) acc[i][j] = 0.0f;

    for (int d4 = 0; d4 < DIN / 4; ++d4) {
        float4 xf[TR];
#pragma unroll
        for (int i = 0; i < TR; ++i)
            xf[i] = x4[(size_t)(base + rg * TR + i) * (DIN / 4) + d4];
        float4 wf[4];
#pragma unroll
        for (int dd = 0; dd < 4; ++dd)
            wf[dd] = *(const float4*)&sWt[4 * d4 + dd][4 * c];
#pragma unroll
        for (int i = 0; i < TR; ++i) {
            acc[i][0] += xf[i].x * wf[0].x + xf[i].y * wf[1].x + xf[i].z * wf[2].x + xf[i].w * wf[3].x;
            acc[i][1] += xf[i].x * wf[0].y + xf[i].y * wf[1].y + xf[i].z * wf[2].y + xf[i].w * wf[3].y;
            acc[i][2] += xf[i].x * wf[0].z + xf[i].y * wf[1].z + xf[i].z * wf[2].z + xf[i].w * wf[3].z;
            acc[i][3] += xf[i].x * wf[0].w + xf[i].y * wf[1].w + xf[i].z * wf[2].w + xf[i].w * wf[3].w;
        }
    }

#pragma unroll
    for (int i = 0; i < TR; ++i) {
        float4 o = {acc[i][0], acc[i][1], acc[i][2], acc[i][3]};
        ((float4*)out)[(size_t)(base + rg * TR + i) * CG + c] = o;
    }
}

// ---------------------------------------------------------------------------
// Kernel 3: online-softmax sparse masked attention, TWO BATCHES PER WAVE.
// Graph is batch-shared, so a wave processes query n for batches (2p, 2p+1)
// with one set of neighbor offsets: iteration count unchanged, fixed
// per-iteration cost (LDS offset read, ballot, loop) amortized 2x, 4 gather
// loads in flight, 2 independent DPP chains. Block = 4 queries x one pair
// (<=4MB of h per XCD L2). Skip-threshold flash update per batch (terms with
// p <= m-100 underflow exp to exactly 0 -> bit-neutral skip); taken path is
// the exact two-sided update for both batches. Exact torch masked_fill(s==0)
// semantics; all-masked fallback per batch = rare in-kernel path.
// ---------------------------------------------------------------------------
template <int D, bool RELU>
__global__ __launch_bounds__(256) void k_attn(
    const float* __restrict__ h, const int* __restrict__ cnt,
    const int* __restrict__ idx, const float* __restrict__ bias,
    float* __restrict__ out)
{
    constexpr int V  = D / 4;    // float4s per row (32 or 16)
    constexpr int NF = V / 16;   // float4s per lane per row (2 or 1)
    constexpr int RB = D * 4;    // row bytes (512 or 256)

    const int bid  = blockIdx.x;
    const int pair = bid & 3;                    // batch pair -> XCD spread
    const int wave = threadIdx.x >> 6;
    const int lane = threadIdx.x & 63;
    const int n    = (bid >> 2) * 4 + wave;      // one query per wave
    const int b0   = 2 * pair, b1 = 2 * pair + 1;
    const int grp  = lane >> 4;                  // 4 neighbor streams
    const int gl   = lane & 15;
    const int gtop = (lane & 48) + 15;           // group's TOP lane

    __shared__ int s_off[4][MAXDEG + 12];        // wave-private byte offsets

    const int k = cnt[n];
    const int* __restrict__ myidx = idx + (size_t)n * MAXDEG;
    for (int j = lane; j < k; j += 64) s_off[wave][j] = myidx[j] * RB;
    if (lane < 12) s_off[wave][k + lane] = 0;    // pad: safe prefetch targets

    const char* __restrict__ hb0 = (const char*)h + (size_t)b0 * N_ * RB;
    const char* __restrict__ hb1 = (const char*)h + (size_t)b1 * N_ * RB;
    const int lb = gl * 16;

    float4 qf0[NF], qf1[NF];
#pragma unroll
    for (int i = 0; i < NF; ++i) {
        qf0[i] = *(const float4*)(hb0 + (size_t)n * RB + lb + 256 * i);
        qf1[i] = *(const float4*)(hb1 + (size_t)n * RB + lb + 256 * i);
    }

    // self-score init per batch (identical in all groups: same gl slots)
    float m0, m1;
    {
        float p0 = 0.0f, p1 = 0.0f;
#pragma unroll
        for (int i = 0; i < NF; ++i) {
            p0 += qf0[i].x * qf0[i].x + qf0[i].y * qf0[i].y
                + qf0[i].z * qf0[i].z + qf0[i].w * qf0[i].w;
            p1 += qf1[i].x * qf1[i].x + qf1[i].y * qf1[i].y
                + qf1[i].z * qf1[i].z + qf1[i].w * qf1[i].w;
        }
        p0 = dpp_reduce16(p0);
        p1 = dpp_reduce16(p1);
        const float pb0 = __shfl(p0, gtop, 64);
        const float pb1 = __shfl(p1, gtop, 64);
        m0 = (pb0 != 0.0f) ? pb0 : -INFINITY;
        m1 = (pb1 != 0.0f) ? pb1 : -INFINITY;
    }
    float mt0 = m0 - 100.0f, mt1 = m1 - 100.0f;
    float s0 = 0.0f, s1 = 0.0f;
    float4 acc0[NF], acc1[NF];
#pragma unroll
    for (int i = 0; i < NF; ++i) {
        acc0[i] = {0.0f, 0.0f, 0.0f, 0.0f};
        acc1[i] = {0.0f, 0.0f, 0.0f, 0.0f};
    }

    auto loadrow = [&](float4 (&r0)[NF], float4 (&r1)[NF], int j) {
        const int off = s_off[wave][j];
#pragma unroll
        for (int i = 0; i < NF; ++i) {
            r0[i] = *(const float4*)(hb0 + off + lb + 256 * i);
            r1[i] = *(const float4*)(hb1 + off + lb + 256 * i);
        }
    };
    auto process = [&](const float4 (&c0)[NF], const float4 (&c1)[NF]) {
        float p0 = 0.0f, p1 = 0.0f;
#pragma unroll
        for (int i = 0; i < NF; ++i) {
            p0 += qf0[i].x * c0[i].x + qf0[i].y * c0[i].y
                + qf0[i].z * c0[i].z + qf0[i].w * c0[i].w;
            p1 += qf1[i].x * c1[i].x + qf1[i].y * c1[i].y
                + qf1[i].z * c1[i].z + qf1[i].w * c1[i].w;
        }
        p0 = dpp_reduce16(p0);                   // independent DPP chains
        p1 = dpp_reduce16(p1);
        const unsigned long long hit =
            (__ballot(p0 > mt0) | __ballot(p1 > mt1)) & GLTOPMASK;
        if (__builtin_expect(hit != 0ULL, 0)) {
            {   // exact flash update, batch 0
                const float pb = __shfl(p0, gtop, 64);
                const bool valid = (pb != 0.0f);
                const float pm = valid ? pb : m0;
                const float nm = fmaxf(m0, pm);
                const float f = (m0 == nm) ? 1.0f : __expf(m0 - nm);
                const float e = valid ? __expf(pb - nm) : 0.0f;
                s0 = s0 * f + e;
#pragma unroll
                for (int i = 0; i < NF; ++i) {
                    acc0[i].x = acc0[i].x * f + e * c0[i].x;
                    acc0[i].y = acc0[i].y * f + e * c0[i].y;
                    acc0[i].z = acc0[i].z * f + e * c0[i].z;
                    acc0[i].w = acc0[i].w * f + e * c0[i].w;
                }
                m0 = nm; mt0 = m0 - 100.0f;
            }
            {   // exact flash update, batch 1
                const float pb = __shfl(p1, gtop, 64);
                const bool valid = (pb != 0.0f);
                const float pm = valid ? pb : m1;
                const float nm = fmaxf(m1, pm);
                const float f = (m1 == nm) ? 1.0f : __expf(m1 - nm);
                const float e = valid ? __expf(pb - nm) : 0.0f;
                s1 = s1 * f + e;
#pragma unroll
                for (int i = 0; i < NF; ++i) {
                    acc1[i].x = acc1[i].x * f + e * c1[i].x;
                    acc1[i].y = acc1[i].y * f + e * c1[i].y;
                    acc1[i].z = acc1[i].z * f + e * c1[i].z;
                    acc1[i].w = acc1[i].w * f + e * c1[i].w;
                }
                m1 = nm; mt1 = m1 - 100.0f;
            }
        }
    };

    // depth-1 double-buffer, unroll-2, no register copies (pads make
    // overshoot loads safe: j+4 <= k+11)
    {
        float4 c0[NF], c1[NF], x0[NF], x1[NF];
        loadrow(c0, c1, grp);
        int j = grp;
        while (j < k) {
            loadrow(x0, x1, j + 4);
            process(c0, c1);
            j += 4; if (j >= k) break;
            loadrow(c0, c1, j + 4);
            process(x0, x1);
            j += 4;
        }
    }

    // merge the 4 group states (xor 16, 32), both batches
#pragma unroll
    for (int mask = 16; mask <= 32; mask <<= 1) {
        const float m0b = __shfl_xor(m0, mask, 64);
        const float s0b = __shfl_xor(s0, mask, 64);
        const float m1b = __shfl_xor(m1, mask, 64);
        const float s1b = __shfl_xor(s1, mask, 64);
        float4 a0b[NF], a1b[NF];
#pragma unroll
        for (int i = 0; i < NF; ++i) {
            a0b[i].x = __shfl_xor(acc0[i].x, mask, 64);
            a0b[i].y = __shfl_xor(acc0[i].y, mask, 64);
            a0b[i].z = __shfl_xor(acc0[i].z, mask, 64);
            a0b[i].w = __shfl_xor(acc0[i].w, mask, 64);
            a1b[i].x = __shfl_xor(acc1[i].x, mask, 64);
            a1b[i].y = __shfl_xor(acc1[i].y, mask, 64);
            a1b[i].z = __shfl_xor(acc1[i].z, mask, 64);
            a1b[i].w = __shfl_xor(acc1[i].w, mask, 64);
        }
        {
            const float mm = fmaxf(m0, m0b);
            const float f1 = (m0  == mm) ? 1.0f : __expf(m0  - mm);
            const float f2 = (m0b == mm) ? 1.0f : __expf(m0b - mm);
            s0 = s0 * f1 + s0b * f2;
#pragma unroll
            for (int i = 0; i < NF; ++i) {
                acc0[i].x = acc0[i].x * f1 + a0b[i].x * f2;
                acc0[i].y = acc0[i].y * f1 + a0b[i].y * f2;
                acc0[i].z = acc0[i].z * f1 + a0b[i].z * f2;
                acc0[i].w = acc0[i].w * f1 + a0b[i].w * f2;
            }
            m0 = mm;
        }
        {
            const float mm = fmaxf(m1, m1b);
            const float f1 = (m1  == mm) ? 1.0f : __expf(m1  - mm);
            const float f2 = (m1b == mm) ? 1.0f : __expf(m1b - mm);
            s1 = s1 * f1 + s1b * f2;
#pragma unroll
            for (int i = 0; i < NF; ++i) {
                acc1[i].x = acc1[i].x * f1 + a1b[i].x * f2;
                acc1[i].y = acc1[i].y * f1 + a1b[i].y * f2;
                acc1[i].z = acc1[i].z * f1 + a1b[i].z * f2;
                acc1[i].w = acc1[i].w * f1 + a1b[i].w * f2;
            }
            m1 = mm;
        }
    }

    const float4* bias4 = (const float4*)bias;

    // ---- batch 0 epilogue ----
    if (s0 > 0.0f) {
        if (grp == 0) {
            const float inv = 1.0f / s0;
#pragma unroll
            for (int i = 0; i < NF; ++i) {
                const float4 bi = bias4[gl + 16 * i];
                float4 o;
                o.x = acc0[i].x * inv + bi.x;
                o.y = acc0[i].y * inv + bi.y;
                o.z = acc0[i].z * inv + bi.z;
                o.w = acc0[i].w * inv + bi.w;
                if (RELU) {
                    o.x = fmaxf(o.x, 0.0f); o.y = fmaxf(o.y, 0.0f);
                    o.z = fmaxf(o.z, 0.0f); o.w = fmaxf(o.w, 0.0f);
                }
                ((float4*)out)[((size_t)b0 * N_ + n) * V + gl + 16 * i] = o;
            }
        }
    } else {
        // RARE: all masked -> uniform softmax = column mean of h[b0]
        const float4* hb4 = (const float4*)hb0;
        constexpr int RS = 64 / V;
        const int sl = lane % V;
        const int rs = lane / V;
        float4 a = {0.0f, 0.0f, 0.0f, 0.0f};
        for (int row = rs; row < N_; row += RS) {
            float4 v = hb4[(size_t)row * V + sl];
            a.x += v.x; a.y += v.y; a.z += v.z; a.w += v.w;
        }
#pragma unroll
        for (int mask = V; mask < 64; mask <<= 1) {
            a.x += __shfl_xor(a.x, mask, 64);
            a.y += __shfl_xor(a.y, mask, 64);
            a.z += __shfl_xor(a.z, mask, 64);
            a.w += __shfl_xor(a.w, mask, 64);
        }
        if (lane < V) {
            constexpr float invN = 1.0f / (float)N_;
            const float4 bi = bias4[sl];
            float4 o;
            o.x = a.x * invN + bi.x;
            o.y = a.y * invN + bi.y;
            o.z = a.z * invN + bi.z;
            o.w = a.w * invN + bi.w;
            if (RELU) {
                o.x = fmaxf(o.x, 0.0f); o.y = fmaxf(o.y, 0.0f);
                o.z = fmaxf(o.z, 0.0f); o.w = fmaxf(o.w, 0.0f);
            }
            ((float4*)out)[((size_t)b0 * N_ + n) * V + sl] = o;
        }
    }

    // ---- batch 1 epilogue ----
    if (s1 > 0.0f) {
        if (grp == 1) {
            const float inv = 1.0f / s1;
#pragma unroll
            for (int i = 0; i < NF; ++i) {
                const float4 bi = bias4[gl + 16 * i];
                float4 o;
                o.x = acc1[i].x * inv + bi.x;
                o.y = acc1[i].y * inv + bi.y;
                o.z = acc1[i].z * inv + bi.z;
                o.w = acc1[i].w * inv + bi.w;
                if (RELU) {
                    o.x = fmaxf(o.x, 0.0f); o.y = fmaxf(o.y, 0.0f);
                    o.z = fmaxf(o.z, 0.0f); o.w = fmaxf(o.w, 0.0f);
                }
                ((float4*)out)[((size_t)b1 * N_ + n) * V + gl + 16 * i] = o;
            }
        }
    } else {
        const float4* hb4 = (const float4*)hb1;
        constexpr int RS = 64 / V;
        const int sl = lane % V;
        const int rs = lane / V;
        float4 a = {0.0f, 0.0f, 0.0f, 0.0f};
        for (int row = rs; row < N_; row += RS) {
            float4 v = hb4[(size_t)row * V + sl];
            a.x += v.x; a.y += v.y; a.z += v.z; a.w += v.w;
        }
#pragma unroll
        for (int mask = V; mask < 64; mask <<= 1) {
            a.x += __shfl_xor(a.x, mask, 64);
            a.y += __shfl_xor(a.y, mask, 64);
            a.z += __shfl_xor(a.z, mask, 64);
            a.w += __shfl_xor(a.w, mask, 64);
        }
        if (lane < V) {
            constexpr float invN = 1.0f / (float)N_;
            const float4 bi = bias4[sl];
            float4 o;
            o.x = a.x * invN + bi.x;
            o.y = a.y * invN + bi.y;
            o.z = a.z * invN + bi.z;
            o.w = a.w * invN + bi.w;
            if (RELU) {
                o.x = fmaxf(o.x, 0.0f); o.y = fmaxf(o.y, 0.0f);
                o.z = fmaxf(o.z, 0.0f); o.w = fmaxf(o.w, 0.0f);
            }
            ((float4*)out)[((size_t)b1 * N_ + n) * V + sl] = o;
        }
    }
}

// ---------------------------------------------------------------------------
// Launch
// ---------------------------------------------------------------------------
extern "C" void kernel_launch(void* const* d_in, const int* in_sizes, int n_in,
                              void* d_out, int out_size, void* d_ws, size_t ws_size,
                              hipStream_t stream) {
    (void)in_sizes; (void)n_in; (void)out_size; (void)ws_size;

    const float* flow_x = (const float*)d_in[0];
    const float* graph  = (const float*)d_in[1];
    const float* W1     = (const float*)d_in[2];
    const float* b1     = (const float*)d_in[3];
    const float* W2     = (const float*)d_in[4];
    const float* b2     = (const float*)d_in[5];
    float* out = (float*)d_out;

    char* p = (char*)d_ws;
    auto carve = [&](size_t bytes) -> void* {
        void* r = (void*)p;
        p += (bytes + 255) & ~(size_t)255;
        return r;
    };
    int*   nbr_cnt = (int*)carve((size_t)N_ * sizeof(int));
    int*   nbr_idx = (int*)carve((size_t)N_ * MAXDEG * sizeof(int));
    float* h1      = (float*)carve((size_t)B_ * N_ * DHID * sizeof(float));
    float* x2      = (float*)carve((size_t)B_ * N_ * DHID * sizeof(float));
    float* h2      = (float*)carve((size_t)B_ * N_ * DOUT2 * sizeof(float));

    // 1. adjacency -> neighbor lists (wave-per-row ballot compaction)
    k_build_csr<<<N_ / 4, 256, 0, stream>>>(graph, nbr_cnt, nbr_idx);

    // 2. layer 1 linear
    k_linear<DIN1, DHID><<<(B_ * N_) / 32, 256, 0, stream>>>(flow_x, W1, h1);

    // 3. layer 1 attention + bias + relu (one query x two batches per wave)
    k_attn<DHID, true><<<N_, 256, 0, stream>>>(h1, nbr_cnt, nbr_idx, b1, x2);

    // 4. layer 2 linear
    k_linear<DHID, DOUT2><<<(B_ * N_) / 32, 256, 0, stream>>>(x2, W2, h2);

    // 5. layer 2 attention + bias -> d_out  ([B,N,1,64] is flat-identical)
    k_attn<DOUT2, false><<<N_, 256, 0, stream>>>(h2, nbr_cnt, nbr_idx, b2, out);
}